// Round 6
// baseline (198.396 us; speedup 1.0000x reference)
//
#include <hip/hip_runtime.h>
#include <hip/hip_bf16.h>
#include <cstdint>

#define DIMD 1024
#define NH 16
#define DHD 64
#define BB 2
#define TT 2048
#define MROWS (BB * TT)   // 4096

typedef unsigned short u16;
typedef unsigned int u32;
typedef __attribute__((ext_vector_type(8))) __bf16 bf16x8;
typedef __attribute__((ext_vector_type(4))) float f32x4;

__device__ __forceinline__ u16 f2bf(float f) {
    union { float f; unsigned int i; } v; v.f = f;
    unsigned int u = v.i;
    unsigned int r = (u + 0x7fffu + ((u >> 16) & 1u)) >> 16;
    return (u16)r;
}
__device__ __forceinline__ int4 pack8(const float4& a, const float4& b) {
    union { int4 v; u16 u[8]; } t;
    t.u[0] = f2bf(a.x); t.u[1] = f2bf(a.y); t.u[2] = f2bf(a.z); t.u[3] = f2bf(a.w);
    t.u[4] = f2bf(b.x); t.u[5] = f2bf(b.y); t.u[6] = f2bf(b.z); t.u[7] = f2bf(b.w);
    return t.v;
}
// async global->LDS, 16B per lane. LDS dest = wave-uniform base + lane*16.
__device__ __forceinline__ void gl_lds16(const u16* g, u16* l) {
    __builtin_amdgcn_global_load_lds(
        (const __attribute__((address_space(1))) u32*)g,
        (__attribute__((address_space(3))) u32*)l, 16, 0, 0);
}

// ---------------------------------------------------------------------------
// One-shot f32 -> bf16 conversion of x, Wq|Wk|Wv (concat), Wo.
// ---------------------------------------------------------------------------
__global__ __launch_bounds__(256) void convert_all(const float* __restrict__ x,
                                                   const float* __restrict__ Wq,
                                                   const float* __restrict__ Wk,
                                                   const float* __restrict__ Wv,
                                                   const float* __restrict__ Wo,
                                                   u16* __restrict__ xb,
                                                   u16* __restrict__ wqkv,
                                                   u16* __restrict__ wob) {
    int t = blockIdx.x * 256 + threadIdx.x;
    const float* src; u16* dst; int rel;
    if (t < 524288)      { src = x;  dst = xb;             rel = t; }
    else if (t < 655360) { src = Wq; dst = wqkv;           rel = t - 524288; }
    else if (t < 786432) { src = Wk; dst = wqkv + 1048576; rel = t - 655360; }
    else if (t < 917504) { src = Wv; dst = wqkv + 2097152; rel = t - 786432; }
    else                 { src = Wo; dst = wob;            rel = t - 917504; }
    size_t e = (size_t)rel * 8;
    float4 a = *(const float4*)(src + e);
    float4 b = *(const float4*)(src + e + 4);
    *(int4*)(dst + e) = pack8(a, b);
}

// ---------------------------------------------------------------------------
// Fused QKV projection + RoPE. C[m,n] = sum_k xb[m,k]*wqkv[n,k], N=3072.
// 128x64 tile, BK=32, single-buffer gl_lds K-loop (R4 structure).
// 4 waves: wave w rows [32w,32w+32), all 64 cols; acc[2][4].
// Grid (48,32) = 1536 blocks -> ~6 blocks/CU.
// ---------------------------------------------------------------------------
__global__ __launch_bounds__(256, 6) void gemm_qkv(const u16* __restrict__ xb,
                                                   const u16* __restrict__ wqkv,
                                                   u16* __restrict__ qb,
                                                   u16* __restrict__ kb,
                                                   u16* __restrict__ vb,
                                                   const float* __restrict__ rot) {
    constexpr int Kd = 1024;
    __shared__ u16 As[128 * 32];
    __shared__ u16 Bs[64 * 32];

    const int tid  = threadIdx.x;
    const int lane = tid & 63;
    const int w    = tid >> 6;
    const int m0   = blockIdx.y * 128;
    const int n0   = blockIdx.x * 64;       // [0, 3072)

    const u16* Ag = xb   + (size_t)(m0 + 32 * w + (lane >> 2)) * Kd + (lane & 3) * 8;
    const u16* Bg = wqkv + (size_t)(n0 + 16 * w + (lane >> 2)) * Kd + (lane & 3) * 8;
    u16* Al0 = &As[(32 * w) * 32];
    u16* Al1 = &As[(32 * w + 16) * 32];
    u16* Bl  = &Bs[(16 * w) * 32];

    const int r16  = lane & 15;
    const int quad = lane >> 4;
    const int q8   = quad * 8;
    const int wm   = w * 32;

    f32x4 acc[2][4];
#pragma unroll
    for (int i = 0; i < 2; i++)
#pragma unroll
        for (int j = 0; j < 4; j++) acc[i][j] = f32x4{0.f, 0.f, 0.f, 0.f};

#pragma unroll 1
    for (int k0 = 0; k0 < Kd; k0 += 32) {
        __syncthreads();
        gl_lds16(Ag + k0, Al0);
        gl_lds16(Ag + 16 * Kd + k0, Al1);
        gl_lds16(Bg + k0, Bl);
        __syncthreads();   // drains vmcnt(0): loads landed

        bf16x8 af[2], bfr[4];
#pragma unroll
        for (int i = 0; i < 2; i++)
            af[i] = *(const bf16x8*)&As[(wm + i * 16 + r16) * 32 + q8];
#pragma unroll
        for (int j = 0; j < 4; j++)
            bfr[j] = *(const bf16x8*)&Bs[(j * 16 + r16) * 32 + q8];
#pragma unroll
        for (int mi = 0; mi < 2; mi++)
#pragma unroll
            for (int ni = 0; ni < 4; ni++)
                acc[mi][ni] = __builtin_amdgcn_mfma_f32_16x16x32_bf16(
                    af[mi], bfr[ni], acc[mi][ni], 0, 0, 0);
    }

    // epilogue. n-tile = exactly one head (64 cols). d = ni*16+r16 (ni<2);
    // rotary pair (d, d+32) = (acc[mi][ni], acc[mi][ni+2]).
    const int wsel = n0 >> 10;
    const int nloc = n0 & 1023;
    u16* C = (wsel == 0) ? qb : (wsel == 1) ? kb : vb;

    if (wsel < 2) {
#pragma unroll
        for (int mi = 0; mi < 2; mi++)
#pragma unroll
            for (int r = 0; r < 4; r++) {
                int row = m0 + wm + mi * 16 + quad * 4 + r;   // = b*T + t
#pragma unroll
                for (int ni = 0; ni < 2; ni++) {
                    int d = ni * 16 + r16;
                    float s0, c0, s1, c1;
                    __sincosf(rot[row * DHD + d], &s0, &c0);
                    __sincosf(rot[row * DHD + d + 32], &s1, &c1);
                    float x0 = acc[mi][ni][r], x1 = acc[mi][ni + 2][r];
                    C[(size_t)row * DIMD + nloc + d]      = f2bf(x0 * c0 - x1 * s0);
                    C[(size_t)row * DIMD + nloc + d + 32] = f2bf(x1 * c1 + x0 * s1);
                }
            }
    } else {
#pragma unroll
        for (int mi = 0; mi < 2; mi++)
#pragma unroll
            for (int ni = 0; ni < 4; ni++)
#pragma unroll
                for (int r = 0; r < 4; r++) {
                    int row = m0 + wm + mi * 16 + quad * 4 + r;
                    C[(size_t)row * DIMD + nloc + ni * 16 + r16] = f2bf(acc[mi][ni][r]);
                }
    }
}

// ---------------------------------------------------------------------------
// V transpose: vb (B,T,H,DH) -> vbT [b][h][d][t]. 64x64 tiles via padded LDS.
// ---------------------------------------------------------------------------
__global__ __launch_bounds__(256) void transpose_v(const u16* __restrict__ vb,
                                                   u16* __restrict__ vbT) {
    __shared__ u16 Ls[64 * 65];
    const int i  = threadIdx.x;
    const int t0 = blockIdx.x * 64;
    const int h  = blockIdx.y;
    const int b  = blockIdx.z;
#pragma unroll
    for (int r = 0; r < 2; r++) {
        int t = r * 32 + (i >> 3);
        int c = (i & 7) * 8;
        union { int4 v; u16 u[8]; } tmp;
        tmp.v = *(const int4*)&vb[(size_t)(b * TT + t0 + t) * DIMD + h * DHD + c];
#pragma unroll
        for (int j = 0; j < 8; j++) Ls[t * 65 + c + j] = tmp.u[j];
    }
    __syncthreads();
#pragma unroll
    for (int r = 0; r < 2; r++) {
        int d  = r * 32 + (i >> 3);
        int tc = (i & 7) * 8;
        union { int4 v; u16 u[8]; } tmp;
#pragma unroll
        for (int j = 0; j < 8; j++) tmp.u[j] = Ls[(tc + j) * 65 + d];
        *(int4*)&vbT[((size_t)(b * NH + h) * DHD + d) * TT + t0 + tc] = tmp.v;
    }
}

// ---------------------------------------------------------------------------
// Windowed causal attention, keys in [q-128, q]. Block = (b,h,64 queries).
// NO staging LDS: Q/K/V^T fragments load directly from global (L2-served).
// Only P round-trips through LDS (per-wave region). One barrier total.
// ---------------------------------------------------------------------------
__global__ __launch_bounds__(256) void attn_kernel(const u16* __restrict__ Q,
                                                   const u16* __restrict__ K,
                                                   const u16* __restrict__ vbT,
                                                   u16* __restrict__ O) {
    constexpr int LDP = 200;
    __shared__ u16 Ps[4 * 16 * LDP];   // 25.6 KB

    const int tid = threadIdx.x;
    const int L   = tid & 63;
    const int w   = tid >> 6;
    const int b   = blockIdx.z;
    const int h   = blockIdx.y;
    const int q0  = blockIdx.x * 64;
    const int kstart = q0 - 128;

    const int r16  = L & 15;
    const int quad = L >> 4;
    const int q8   = quad * 8;

    // Q fragments direct from global: rows q0+w*16+r16, k = {q8, 32+q8}
    const size_t qrow = (size_t)(b * TT + q0 + w * 16 + r16) * DIMD + h * DHD;
    bf16x8 aq0 = *(const bf16x8*)&Q[qrow + q8];
    bf16x8 aq1 = *(const bf16x8*)&Q[qrow + 32 + q8];

    float st[12][4];
    float rmax[4] = {-1e30f, -1e30f, -1e30f, -1e30f};
    const float SC = 0.125f;   // 1/sqrt(64)

#pragma unroll
    for (int kt = 0; kt < 12; kt++) {
        int ka = kstart + kt * 16 + r16;          // key index for mask
        int kc = ka < 0 ? 0 : ka;                 // clamped (masked later)
        const size_t krow = (size_t)(b * TT + kc) * DIMD + h * DHD;
        bf16x8 bk0 = *(const bf16x8*)&K[krow + q8];
        bf16x8 bk1 = *(const bf16x8*)&K[krow + 32 + q8];
        f32x4 s = f32x4{0.f, 0.f, 0.f, 0.f};
        s = __builtin_amdgcn_mfma_f32_16x16x32_bf16(aq0, bk0, s, 0, 0, 0);
        s = __builtin_amdgcn_mfma_f32_16x16x32_bf16(aq1, bk1, s, 0, 0, 0);
#pragma unroll
        for (int r = 0; r < 4; r++) {
            int qa = q0 + w * 16 + quad * 4 + r;
            float sv = s[r] * SC;
            bool ok = (ka >= 0) && (ka <= qa) && (ka >= qa - 128);
            sv = ok ? sv : -1e30f;
            st[kt][r] = sv;
            rmax[r] = fmaxf(rmax[r], sv);
        }
    }
#pragma unroll
    for (int off = 8; off >= 1; off >>= 1)
#pragma unroll
        for (int r = 0; r < 4; r++)
            rmax[r] = fmaxf(rmax[r], __shfl_xor(rmax[r], off, 64));

    // P into per-wave LDS region (C-layout -> A-layout transform)
    u16* Pw = &Ps[w * 16 * LDP];
    float rsum[4] = {0.f, 0.f, 0.f, 0.f};
#pragma unroll
    for (int kt = 0; kt < 12; kt++)
#pragma unroll
        for (int r = 0; r < 4; r++) {
            float p = __expf(st[kt][r] - rmax[r]);
            rsum[r] += p;
            Pw[(quad * 4 + r) * LDP + kt * 16 + r16] = f2bf(p);
        }
#pragma unroll
    for (int off = 8; off >= 1; off >>= 1)
#pragma unroll
        for (int r = 0; r < 4; r++)
            rsum[r] += __shfl_xor(rsum[r], off, 64);
    float rinv[4];
#pragma unroll
    for (int r = 0; r < 4; r++) rinv[r] = 1.0f / rsum[r];

    __syncthreads();   // P visible (also orders the u16->bf16x8 aliasing)

    bf16x8 pa[6];
#pragma unroll
    for (int kc = 0; kc < 6; kc++)
        pa[kc] = *(const bf16x8*)&Pw[r16 * LDP + kc * 32 + q8];

    // PV: V^T fragments direct from global vbT[b][h][d][t]
    const size_t vbase = (size_t)(b * NH + h) * DHD * TT;
#pragma unroll
    for (int nt = 0; nt < 4; nt++) {
        f32x4 acc = f32x4{0.f, 0.f, 0.f, 0.f};
        const size_t vrow = vbase + (size_t)(nt * 16 + r16) * TT;
#pragma unroll
        for (int kc = 0; kc < 6; kc++) {
            int kcol = kstart + kc * 32 + q8;
            if (kcol < 0) kcol = 0;               // masked (P=0) lanes
            bf16x8 bv = *(const bf16x8*)&vbT[vrow + kcol];
            acc = __builtin_amdgcn_mfma_f32_16x16x32_bf16(pa[kc], bv, acc, 0, 0, 0);
        }
#pragma unroll
        for (int r = 0; r < 4; r++) {
            int qa = q0 + w * 16 + quad * 4 + r;
            O[(size_t)(b * TT + qa) * DIMD + h * DHD + nt * 16 + r16] =
                f2bf(acc[r] * rinv[r]);
        }
    }
}

// ---------------------------------------------------------------------------
// Output projection: C = A @ Wo^T, A bf16 4096x1024, Wo bf16, C f32.
// 64x128 tile, single-buffer gl_lds K-loop (R4). Grid (8,64) = 512 blocks.
// ---------------------------------------------------------------------------
__global__ __launch_bounds__(256) void gemm_out(const u16* __restrict__ A,
                                                const u16* __restrict__ Wb,
                                                float* __restrict__ C) {
    constexpr int Kd = 1024, Nd = 1024;
    __shared__ u16 As[64 * 32];
    __shared__ u16 Bs[128 * 32];

    const int tid  = threadIdx.x;
    const int lane = tid & 63;
    const int w    = tid >> 6;
    const int m0   = blockIdx.y * 64;
    const int n0   = blockIdx.x * 128;

    const u16* Ag = A  + (size_t)(m0 + 16 * w + (lane >> 2)) * Kd + (lane & 3) * 8;
    const u16* Bg = Wb + (size_t)(n0 + 32 * w + (lane >> 2)) * Kd + (lane & 3) * 8;
    u16* Al  = &As[(16 * w) * 32];
    u16* Bl0 = &Bs[(32 * w) * 32];
    u16* Bl1 = &Bs[(32 * w + 16) * 32];

    const int r16  = lane & 15;
    const int quad = lane >> 4;
    const int q8   = quad * 8;
    const int cb   = (w >> 1) * 64 + (w & 1) * 16;

    f32x4 acc[4][2];
#pragma unroll
    for (int i = 0; i < 4; i++)
#pragma unroll
        for (int j = 0; j < 2; j++) acc[i][j] = f32x4{0.f, 0.f, 0.f, 0.f};

#pragma unroll 1
    for (int k0 = 0; k0 < Kd; k0 += 32) {
        __syncthreads();
        gl_lds16(Ag + k0, Al);
        gl_lds16(Bg + k0, Bl0);
        gl_lds16(Bg + 16 * Kd + k0, Bl1);
        __syncthreads();

        bf16x8 af[4], bfr[2];
#pragma unroll
        for (int i = 0; i < 4; i++)
            af[i] = *(const bf16x8*)&As[(i * 16 + r16) * 32 + q8];
#pragma unroll
        for (int j = 0; j < 2; j++)
            bfr[j] = *(const bf16x8*)&Bs[(cb + j * 32 + r16) * 32 + q8];
#pragma unroll
        for (int mi = 0; mi < 4; mi++)
#pragma unroll
            for (int ni = 0; ni < 2; ni++)
                acc[mi][ni] = __builtin_amdgcn_mfma_f32_16x16x32_bf16(
                    af[mi], bfr[ni], acc[mi][ni], 0, 0, 0);
    }

#pragma unroll
    for (int mi = 0; mi < 4; mi++)
#pragma unroll
        for (int j = 0; j < 2; j++)
#pragma unroll
            for (int r = 0; r < 4; r++) {
                int row = m0 + mi * 16 + quad * 4 + r;
                C[(size_t)row * Nd + n0 + cb + j * 32 + r16] = acc[mi][j][r];
            }
}

// ---------------------------------------------------------------------------
extern "C" void kernel_launch(void* const* d_in, const int* in_sizes, int n_in,
                              void* d_out, int out_size, void* d_ws, size_t ws_size,
                              hipStream_t stream) {
    const float* x   = (const float*)d_in[0];
    const float* rot = (const float*)d_in[2];
    const float* Wq  = (const float*)d_in[3];
    const float* Wk  = (const float*)d_in[4];
    const float* Wv  = (const float*)d_in[5];
    const float* Wo  = (const float*)d_in[6];
    float* out = (float*)d_out;

    u16* xb   = (u16*)d_ws;               // 4M u16
    u16* wqkv = xb + 4194304;             // 3M
    u16* wob  = wqkv + 3145728;           // 1M
    u16* qb   = wob + 1048576;            // 4M
    u16* kb   = qb + 4194304;             // 4M
    u16* vb   = kb + 4194304;             // 4M
    u16* ab   = vb + 4194304;             // 4M
    u16* vbT  = ab + 4194304;             // 4M  (total 56 MB)

    convert_all<<<4096, 256, 0, stream>>>(x, Wq, Wk, Wv, Wo, xb, wqkv, wob);
    gemm_qkv<<<dim3(3 * DIMD / 64, MROWS / 128), 256, 0, stream>>>(
        xb, wqkv, qb, kb, vb, rot);
    transpose_v<<<dim3(TT / 64, NH, BB), 256, 0, stream>>>(vb, vbT);
    attn_kernel<<<dim3(TT / 64, NH, BB), 256, 0, stream>>>(qb, kb, vbT, ab);
    gemm_out<<<dim3(DIMD / 128, MROWS / 64), 256, 0, stream>>>(ab, wob, out);
}

// Round 7
// 189.446 us; speedup vs baseline: 1.0472x; 1.0472x over previous
//
#include <hip/hip_runtime.h>
#include <hip/hip_bf16.h>
#include <cstdint>

#define DIMD 1024
#define NH 16
#define DHD 64
#define BB 2
#define TT 2048
#define MROWS (BB * TT)   // 4096

typedef unsigned short u16;
typedef unsigned int u32;
typedef __attribute__((ext_vector_type(8))) __bf16 bf16x8;
typedef __attribute__((ext_vector_type(4))) float f32x4;

__device__ __forceinline__ u16 f2bf(float f) {
    union { float f; unsigned int i; } v; v.f = f;
    unsigned int u = v.i;
    unsigned int r = (u + 0x7fffu + ((u >> 16) & 1u)) >> 16;
    return (u16)r;
}
__device__ __forceinline__ int4 pack8(const float4& a, const float4& b) {
    union { int4 v; u16 u[8]; } t;
    t.u[0] = f2bf(a.x); t.u[1] = f2bf(a.y); t.u[2] = f2bf(a.z); t.u[3] = f2bf(a.w);
    t.u[4] = f2bf(b.x); t.u[5] = f2bf(b.y); t.u[6] = f2bf(b.z); t.u[7] = f2bf(b.w);
    return t.v;
}
// async global->LDS, 16B per lane. LDS dest = wave-uniform base + lane*16.
__device__ __forceinline__ void gl_lds16(const u16* g, u16* l) {
    __builtin_amdgcn_global_load_lds(
        (const __attribute__((address_space(1))) u32*)g,
        (__attribute__((address_space(3))) u32*)l, 16, 0, 0);
}

// ---------------------------------------------------------------------------
// One-shot f32 -> bf16 conversion of x, Wq|Wk|Wv (concat), Wo.
// ---------------------------------------------------------------------------
__global__ __launch_bounds__(256) void convert_all(const float* __restrict__ x,
                                                   const float* __restrict__ Wq,
                                                   const float* __restrict__ Wk,
                                                   const float* __restrict__ Wv,
                                                   const float* __restrict__ Wo,
                                                   u16* __restrict__ xb,
                                                   u16* __restrict__ wqkv,
                                                   u16* __restrict__ wob) {
    int t = blockIdx.x * 256 + threadIdx.x;
    const float* src; u16* dst; int rel;
    if (t < 524288)      { src = x;  dst = xb;             rel = t; }
    else if (t < 655360) { src = Wq; dst = wqkv;           rel = t - 524288; }
    else if (t < 786432) { src = Wk; dst = wqkv + 1048576; rel = t - 655360; }
    else if (t < 917504) { src = Wv; dst = wqkv + 2097152; rel = t - 786432; }
    else                 { src = Wo; dst = wob;            rel = t - 917504; }
    size_t e = (size_t)rel * 8;
    float4 a = *(const float4*)(src + e);
    float4 b = *(const float4*)(src + e + 4);
    *(int4*)(dst + e) = pack8(a, b);
}

// ---------------------------------------------------------------------------
// Fused QKV projection + RoPE + V-transpose epilogue.
// C[m,n] = sum_k xb[m,k]*wqkv[n,k], N=3072. 128x128 tile, BK=64 as two
// 32-wide panels staged under ONE barrier pair (16 barrier-pairs total).
// Q/K written (B,T,H,DH) with RoPE; V written transposed [b][h][d][t].
// Grid (24,32) = 768 blocks.
// ---------------------------------------------------------------------------
__global__ __launch_bounds__(256) void gemm_qkv(const u16* __restrict__ xb,
                                                const u16* __restrict__ wqkv,
                                                u16* __restrict__ qb,
                                                u16* __restrict__ kb,
                                                u16* __restrict__ vbT,
                                                const float* __restrict__ rot) {
    constexpr int Kd = 1024;
    __shared__ u16 As[2][128 * 32];
    __shared__ u16 Bs[2][128 * 32];

    const int tid  = threadIdx.x;
    const int lane = tid & 63;
    const int w    = tid >> 6;
    const int m0   = blockIdx.y * 128;
    const int n0   = blockIdx.x * 128;      // [0, 3072)

    const u16* Ag = xb   + (size_t)(m0 + 32 * w + (lane >> 2)) * Kd + (lane & 3) * 8;
    const u16* Bg = wqkv + (size_t)(n0 + 32 * w + (lane >> 2)) * Kd + (lane & 3) * 8;
    const int loff0 = (32 * w) * 32;
    const int loff1 = (32 * w + 16) * 32;

    const int r16  = lane & 15;
    const int quad = lane >> 4;
    const int q8   = quad * 8;
    const int wm   = (w >> 1) * 64;
    const int wn   = (w & 1) * 64;

    f32x4 acc[4][4];
#pragma unroll
    for (int i = 0; i < 4; i++)
#pragma unroll
        for (int j = 0; j < 4; j++) acc[i][j] = f32x4{0.f, 0.f, 0.f, 0.f};

#pragma unroll 1
    for (int k0 = 0; k0 < Kd; k0 += 64) {
        __syncthreads();
        // stage panel 0 (k0) and panel 1 (k0+32): 8 gl_lds, one drain
        gl_lds16(Ag + k0, &As[0][loff0]);
        gl_lds16(Ag + 16 * Kd + k0, &As[0][loff1]);
        gl_lds16(Bg + k0, &Bs[0][loff0]);
        gl_lds16(Bg + 16 * Kd + k0, &Bs[0][loff1]);
        gl_lds16(Ag + k0 + 32, &As[1][loff0]);
        gl_lds16(Ag + 16 * Kd + k0 + 32, &As[1][loff1]);
        gl_lds16(Bg + k0 + 32, &Bs[1][loff0]);
        gl_lds16(Bg + 16 * Kd + k0 + 32, &Bs[1][loff1]);
        __syncthreads();

#pragma unroll
        for (int p = 0; p < 2; p++) {
            bf16x8 af[4], bfr[4];
#pragma unroll
            for (int i = 0; i < 4; i++)
                af[i] = *(const bf16x8*)&As[p][(wm + i * 16 + r16) * 32 + q8];
#pragma unroll
            for (int j = 0; j < 4; j++)
                bfr[j] = *(const bf16x8*)&Bs[p][(wn + j * 16 + r16) * 32 + q8];
#pragma unroll
            for (int mi = 0; mi < 4; mi++)
#pragma unroll
                for (int ni = 0; ni < 4; ni++)
                    acc[mi][ni] = __builtin_amdgcn_mfma_f32_16x16x32_bf16(
                        af[mi], bfr[ni], acc[mi][ni], 0, 0, 0);
        }
    }

    // epilogue. col = n0 + wn + ni*16 + r16.
    const int wsel = n0 >> 10;
    const int nloc = (n0 & 1023) + wn;      // [0,1024), head = col>>6

    if (wsel < 2) {
        // RoPE: within-head d = ni*16+r16 (ni<2); pair = acc[..][ni]/[ni+2]
        u16* C = (wsel == 0) ? qb : kb;
#pragma unroll
        for (int mi = 0; mi < 4; mi++)
#pragma unroll
            for (int r = 0; r < 4; r++) {
                int row = m0 + wm + mi * 16 + quad * 4 + r;   // = b*T + t
#pragma unroll
                for (int ni = 0; ni < 2; ni++) {
                    int d = ni * 16 + r16;
                    float s0, c0, s1, c1;
                    __sincosf(rot[row * DHD + d], &s0, &c0);
                    __sincosf(rot[row * DHD + d + 32], &s1, &c1);
                    float x0 = acc[mi][ni][r], x1 = acc[mi][ni + 2][r];
                    C[(size_t)row * DIMD + nloc + d]      = f2bf(x0 * c0 - x1 * s0);
                    C[(size_t)row * DIMD + nloc + d + 32] = f2bf(x1 * c1 + x0 * s1);
                }
            }
    } else {
        // V transposed: vbT[((b*NH+h)*DHD + d)*TT + t]
#pragma unroll
        for (int mi = 0; mi < 4; mi++)
#pragma unroll
            for (int ni = 0; ni < 4; ni++)
#pragma unroll
                for (int r = 0; r < 4; r++) {
                    int row = m0 + wm + mi * 16 + quad * 4 + r;
                    int b   = row >> 11;
                    int t   = row & (TT - 1);
                    int col = nloc + ni * 16 + r16;
                    int h   = col >> 6;
                    int d   = col & 63;
                    vbT[((size_t)(b * NH + h) * DHD + d) * TT + t] =
                        f2bf(acc[mi][ni][r]);
                }
    }
}

// ---------------------------------------------------------------------------
// Windowed causal attention: keys in [q-128, q]. Block = (b, h, 64 queries).
// Q/K staged row-major (padded); V^T staged from pre-transposed vbT with
// vectorized ds_write_b128. P round-trips through Ks region.
// ---------------------------------------------------------------------------
__global__ __launch_bounds__(256) void attn_kernel(const u16* __restrict__ Q,
                                                   const u16* __restrict__ K,
                                                   const u16* __restrict__ vbT,
                                                   u16* __restrict__ O) {
    constexpr int LDK = 72;    // 64 + 8 pad
    constexpr int LDV = 200;   // 192 + 8 pad
    __shared__ u16 Ks[192 * LDK];      // reused as P (4 waves x 16 x LDV)
    __shared__ u16 Qs[64 * LDK];
    __shared__ u16 VTs[64 * LDV];      // [d][key], key window = 192

    const int tid = threadIdx.x;
    const int L   = tid & 63;
    const int w   = tid >> 6;
    const int b   = blockIdx.z;
    const int h   = blockIdx.y;
    const int q0  = blockIdx.x * 64;
    const int kstart = q0 - 128;

    for (int i = tid; i < 512; i += 256) {
        int qr = i >> 3, c = (i & 7) * 8;
        *(int4*)&Qs[qr * LDK + c] =
            *(const int4*)&Q[(size_t)(b * TT + q0 + qr) * DIMD + h * DHD + c];
    }
    for (int i = tid; i < 1536; i += 256) {
        int kr = i >> 3, c = (i & 7) * 8;
        int kk = kstart + kr;
        int4 val = make_int4(0, 0, 0, 0);
        if (kk >= 0)
            val = *(const int4*)&K[(size_t)(b * TT + kk) * DIMD + h * DHD + c];
        *(int4*)&Ks[kr * LDK + c] = val;
    }
    // V^T: 64 d-rows x 192 keys; vectorized 16B loads+writes (6 per thread)
    for (int i = tid; i < 1536; i += 256) {
        int d = i / 24;
        int c = (i % 24) * 8;            // key offset within window
        int kk = kstart + c;             // multiple of 8; <0 => all 8 <0
        int4 val = make_int4(0, 0, 0, 0);
        if (kk >= 0)
            val = *(const int4*)&vbT[((size_t)(b * NH + h) * DHD + d) * TT + kk];
        *(int4*)&VTs[d * LDV + c] = val;
    }
    __syncthreads();

    const int r16  = L & 15;
    const int quad = L >> 4;
    const int q8   = quad * 8;

    bf16x8 aq0 = *(const bf16x8*)&Qs[(w * 16 + r16) * LDK + q8];
    bf16x8 aq1 = *(const bf16x8*)&Qs[(w * 16 + r16) * LDK + 32 + q8];

    float st[12][4];
    float rmax[4] = {-1e30f, -1e30f, -1e30f, -1e30f};
    const float SC = 0.125f;   // 1/sqrt(64)

#pragma unroll
    for (int kt = 0; kt < 12; kt++) {
        bf16x8 bk0 = *(const bf16x8*)&Ks[(kt * 16 + r16) * LDK + q8];
        bf16x8 bk1 = *(const bf16x8*)&Ks[(kt * 16 + r16) * LDK + 32 + q8];
        f32x4 s = f32x4{0.f, 0.f, 0.f, 0.f};
        s = __builtin_amdgcn_mfma_f32_16x16x32_bf16(aq0, bk0, s, 0, 0, 0);
        s = __builtin_amdgcn_mfma_f32_16x16x32_bf16(aq1, bk1, s, 0, 0, 0);
        int ka = kstart + kt * 16 + r16;
#pragma unroll
        for (int r = 0; r < 4; r++) {
            int qa = q0 + w * 16 + quad * 4 + r;
            float sv = s[r] * SC;
            bool ok = (ka >= 0) && (ka <= qa) && (ka >= qa - 128);
            sv = ok ? sv : -1e30f;
            st[kt][r] = sv;
            rmax[r] = fmaxf(rmax[r], sv);
        }
    }
#pragma unroll
    for (int off = 8; off >= 1; off >>= 1)
#pragma unroll
        for (int r = 0; r < 4; r++)
            rmax[r] = fmaxf(rmax[r], __shfl_xor(rmax[r], off, 64));

    __syncthreads();   // all waves done reading Ks; safe to overwrite as P

    u16* Ps = &Ks[w * 16 * LDV];
    float rsum[4] = {0.f, 0.f, 0.f, 0.f};
#pragma unroll
    for (int kt = 0; kt < 12; kt++)
#pragma unroll
        for (int r = 0; r < 4; r++) {
            float p = __expf(st[kt][r] - rmax[r]);
            rsum[r] += p;
            Ps[(quad * 4 + r) * LDV + kt * 16 + r16] = f2bf(p);
        }
#pragma unroll
    for (int off = 8; off >= 1; off >>= 1)
#pragma unroll
        for (int r = 0; r < 4; r++)
            rsum[r] += __shfl_xor(rsum[r], off, 64);
    float rinv[4];
#pragma unroll
    for (int r = 0; r < 4; r++) rinv[r] = 1.0f / rsum[r];

    __syncthreads();

    bf16x8 pa[6];
#pragma unroll
    for (int kc = 0; kc < 6; kc++)
        pa[kc] = *(const bf16x8*)&Ps[r16 * LDV + kc * 32 + q8];

#pragma unroll
    for (int nt = 0; nt < 4; nt++) {
        f32x4 acc = f32x4{0.f, 0.f, 0.f, 0.f};
#pragma unroll
        for (int kc = 0; kc < 6; kc++) {
            bf16x8 bv = *(const bf16x8*)&VTs[(nt * 16 + r16) * LDV + kc * 32 + q8];
            acc = __builtin_amdgcn_mfma_f32_16x16x32_bf16(pa[kc], bv, acc, 0, 0, 0);
        }
#pragma unroll
        for (int r = 0; r < 4; r++) {
            int qa = q0 + w * 16 + quad * 4 + r;
            O[(size_t)(b * TT + qa) * DIMD + h * DHD + nt * 16 + r16] =
                f2bf(acc[r] * rinv[r]);
        }
    }
}

// ---------------------------------------------------------------------------
// Output projection: C = A @ Wo^T, A bf16 4096x1024, Wo bf16, C f32.
// 64x128 tile, single-buffer gl_lds K-loop. Grid (8,64) = 512 blocks.
// ---------------------------------------------------------------------------
__global__ __launch_bounds__(256) void gemm_out(const u16* __restrict__ A,
                                                const u16* __restrict__ Wb,
                                                float* __restrict__ C) {
    constexpr int Kd = 1024, Nd = 1024;
    __shared__ u16 As[64 * 32];
    __shared__ u16 Bs[128 * 32];

    const int tid  = threadIdx.x;
    const int lane = tid & 63;
    const int w    = tid >> 6;
    const int m0   = blockIdx.y * 64;
    const int n0   = blockIdx.x * 128;

    const u16* Ag = A  + (size_t)(m0 + 16 * w + (lane >> 2)) * Kd + (lane & 3) * 8;
    const u16* Bg = Wb + (size_t)(n0 + 32 * w + (lane >> 2)) * Kd + (lane & 3) * 8;
    u16* Al  = &As[(16 * w) * 32];
    u16* Bl0 = &Bs[(32 * w) * 32];
    u16* Bl1 = &Bs[(32 * w + 16) * 32];

    const int r16  = lane & 15;
    const int quad = lane >> 4;
    const int q8   = quad * 8;
    const int cb   = (w >> 1) * 64 + (w & 1) * 16;

    f32x4 acc[4][2];
#pragma unroll
    for (int i = 0; i < 4; i++)
#pragma unroll
        for (int j = 0; j < 2; j++) acc[i][j] = f32x4{0.f, 0.f, 0.f, 0.f};

#pragma unroll 1
    for (int k0 = 0; k0 < Kd; k0 += 32) {
        __syncthreads();
        gl_lds16(Ag + k0, Al);
        gl_lds16(Bg + k0, Bl0);
        gl_lds16(Bg + 16 * Kd + k0, Bl1);
        __syncthreads();

        bf16x8 af[4], bfr[2];
#pragma unroll
        for (int i = 0; i < 4; i++)
            af[i] = *(const bf16x8*)&As[(i * 16 + r16) * 32 + q8];
#pragma unroll
        for (int j = 0; j < 2; j++)
            bfr[j] = *(const bf16x8*)&Bs[(cb + j * 32 + r16) * 32 + q8];
#pragma unroll
        for (int mi = 0; mi < 4; mi++)
#pragma unroll
            for (int ni = 0; ni < 2; ni++)
                acc[mi][ni] = __builtin_amdgcn_mfma_f32_16x16x32_bf16(
                    af[mi], bfr[ni], acc[mi][ni], 0, 0, 0);
    }

#pragma unroll
    for (int mi = 0; mi < 4; mi++)
#pragma unroll
        for (int j = 0; j < 2; j++)
#pragma unroll
            for (int r = 0; r < 4; r++) {
                int row = m0 + mi * 16 + quad * 4 + r;
                C[(size_t)row * Nd + n0 + cb + j * 32 + r16] = acc[mi][j][r];
            }
}

// ---------------------------------------------------------------------------
extern "C" void kernel_launch(void* const* d_in, const int* in_sizes, int n_in,
                              void* d_out, int out_size, void* d_ws, size_t ws_size,
                              hipStream_t stream) {
    const float* x   = (const float*)d_in[0];
    const float* rot = (const float*)d_in[2];
    const float* Wq  = (const float*)d_in[3];
    const float* Wk  = (const float*)d_in[4];
    const float* Wv  = (const float*)d_in[5];
    const float* Wo  = (const float*)d_in[6];
    float* out = (float*)d_out;

    u16* xb   = (u16*)d_ws;               // 4M u16
    u16* wqkv = xb + 4194304;             // 3M
    u16* wob  = wqkv + 3145728;           // 1M
    u16* qb   = wob + 1048576;            // 4M
    u16* kb   = qb + 4194304;             // 4M
    u16* vbT  = kb + 4194304;             // 4M  ([b][h][d][t])
    u16* ab   = vbT + 4194304;            // 4M  (total 48 MB)

    convert_all<<<4096, 256, 0, stream>>>(x, Wq, Wk, Wv, Wo, xb, wqkv, wob);
    gemm_qkv<<<dim3(3 * DIMD / 128, MROWS / 128), 256, 0, stream>>>(
        xb, wqkv, qb, kb, vbT, rot);
    attn_kernel<<<dim3(TT / 64, NH, BB), 256, 0, stream>>>(qb, kb, vbT, ab);
    gemm_out<<<dim3(DIMD / 128, MROWS / 64), 256, 0, stream>>>(ab, wob, out);
}